// Round 1
// baseline (531.458 us; speedup 1.0000x reference)
//
#include <hip/hip_runtime.h>
#include <stdint.h>

#define NLBL      4096
#define HALF_ROWS 8192
#define HALF_CNT  33554432u   // B*NL/2 = 2^25

__device__ __forceinline__ uint32_t rotl32(uint32_t x, uint32_t r) {
    return (x << r) | (x >> (32u - r));
}

// JAX threefry2x32 with key (0, 42)  [jax.random.key(42)]
__device__ __forceinline__ void threefry2x32(uint32_t x0, uint32_t x1,
                                             uint32_t& o0, uint32_t& o1) {
    const uint32_t ks0 = 0u;
    const uint32_t ks1 = 42u;
    const uint32_t ks2 = 0x1BD11BDAu ^ ks0 ^ ks1;
    x0 += ks0; x1 += ks1;
#define TF_RND(r) x0 += x1; x1 = rotl32(x1, (r)); x1 ^= x0;
    TF_RND(13u) TF_RND(15u) TF_RND(26u) TF_RND(6u)
    x0 += ks1; x1 += ks2 + 1u;
    TF_RND(17u) TF_RND(29u) TF_RND(16u) TF_RND(24u)
    x0 += ks2; x1 += ks0 + 2u;
    TF_RND(13u) TF_RND(15u) TF_RND(26u) TF_RND(6u)
    x0 += ks0; x1 += ks1 + 3u;
    TF_RND(17u) TF_RND(29u) TF_RND(16u) TF_RND(24u)
    x0 += ks1; x1 += ks2 + 4u;
    TF_RND(13u) TF_RND(15u) TF_RND(26u) TF_RND(6u)
    x0 += ks2; x1 += ks0 + 5u;
#undef TF_RND
    o0 = x0; o1 = x1;
}

// JAX uniform [0,1): bitcast((bits>>9) | 0x3F800000) - 1.0f   (exact, monotone in bits>>9)
__device__ __forceinline__ float bits_to_unif(uint32_t b) {
    return __uint_as_float((b >> 9) | 0x3F800000u) - 1.0f;
}

__global__ void __launch_bounds__(256)
warp_loss_main(const float* __restrict__ inputs,
               const float* __restrict__ targets,
               float* __restrict__ out)
{
    const int b   = blockIdx.x;            // row pair (b, b+8192)
    const int tid = threadIdx.x;
    const size_t r0 = (size_t)b * NLBL;
    const size_t r1 = (size_t)(b + HALF_ROWS) * NLBL;

    const float4* in0 = reinterpret_cast<const float4*>(inputs  + r0);
    const float4* in1 = reinterpret_cast<const float4*>(inputs  + r1);
    const float4* tg0 = reinterpret_cast<const float4*>(targets + r0);
    const float4* tg1 = reinterpret_cast<const float4*>(targets + r1);

    __shared__ int                s_pos[2];
    __shared__ float              s_psc[2];
    __shared__ unsigned long long s_key[2][4];
    __shared__ int                s_cnt[2][4];
    __shared__ int                s_cstar[2];
    __shared__ float              s_nstar[2];
    __shared__ float              s_sstar[2];

    float sc0[16], sc1[16], nz0[16], nz1[16];
    const uint32_t cbase0 = (uint32_t)b * NLBL;

    #pragma unroll
    for (int kc = 0; kc < 4; ++kc) {
        const int v4 = tid + (kc << 8);          // float4 index within the row
        const float4 t0 = tg0[v4];
        const float4 t1 = tg1[v4];
        const float4 a0 = in0[v4];
        const float4 a1 = in1[v4];
        const int c = v4 << 2;

        sc0[kc*4+0] = a0.x; sc0[kc*4+1] = a0.y; sc0[kc*4+2] = a0.z; sc0[kc*4+3] = a0.w;
        sc1[kc*4+0] = a1.x; sc1[kc*4+1] = a1.y; sc1[kc*4+2] = a1.z; sc1[kc*4+3] = a1.w;

        if (t0.x > 0.5f) { s_pos[0] = c + 0; s_psc[0] = a0.x; }
        if (t0.y > 0.5f) { s_pos[0] = c + 1; s_psc[0] = a0.y; }
        if (t0.z > 0.5f) { s_pos[0] = c + 2; s_psc[0] = a0.z; }
        if (t0.w > 0.5f) { s_pos[0] = c + 3; s_psc[0] = a0.w; }
        if (t1.x > 0.5f) { s_pos[1] = c + 0; s_psc[1] = a1.x; }
        if (t1.y > 0.5f) { s_pos[1] = c + 1; s_psc[1] = a1.y; }
        if (t1.z > 0.5f) { s_pos[1] = c + 2; s_psc[1] = a1.z; }
        if (t1.w > 0.5f) { s_pos[1] = c + 3; s_psc[1] = a1.w; }

        #pragma unroll
        for (int j = 0; j < 4; ++j) {
            const uint32_t i = cbase0 + (uint32_t)(c + j);
            uint32_t o0, o1;
            threefry2x32(i, i + HALF_CNT, o0, o1);
            nz0[kc*4+j] = bits_to_unif(o0);
            nz1[kc*4+j] = bits_to_unif(o1);
        }
    }
    __syncthreads();

    const int   pos0 = s_pos[0], pos1 = s_pos[1];
    const float psc0 = s_psc[0], psc1 = s_psc[1];

    // Find best-noise hit column per row: hit = ((1+score)-pos_score) > 0, c != pos.
    // key packs (valid<<63 | noise_bits<<12 | (4095-c)) so max-key == (max noise, tie min c).
    unsigned long long key0 = 0ull, key1 = 0ull;
    #pragma unroll
    for (int k = 0; k < 16; ++k) {
        const int c = ((tid + ((k >> 2) << 8)) << 2) | (k & 3);
        const float m0 = (1.0f + sc0[k]) - psc0;   // exact JAX op order
        const float m1 = (1.0f + sc1[k]) - psc1;
        if (c != pos0 && m0 > 0.0f) {
            const unsigned long long kk = (1ull << 63)
                | ((unsigned long long)__float_as_uint(nz0[k]) << 12)
                | (unsigned long long)(4095 - c);
            if (kk > key0) key0 = kk;
        }
        if (c != pos1 && m1 > 0.0f) {
            const unsigned long long kk = (1ull << 63)
                | ((unsigned long long)__float_as_uint(nz1[k]) << 12)
                | (unsigned long long)(4095 - c);
            if (kk > key1) key1 = kk;
        }
    }
    #pragma unroll
    for (int off = 32; off; off >>= 1) {
        const unsigned long long q0 = __shfl_xor(key0, off);
        const unsigned long long q1 = __shfl_xor(key1, off);
        if (q0 > key0) key0 = q0;
        if (q1 > key1) key1 = q1;
    }
    const int wv = tid >> 6;
    if ((tid & 63) == 0) { s_key[0][wv] = key0; s_key[1][wv] = key1; }
    __syncthreads();
    if (tid == 0) {
        #pragma unroll
        for (int r = 0; r < 2; ++r) {
            unsigned long long kk = s_key[r][0];
            if (s_key[r][1] > kk) kk = s_key[r][1];
            if (s_key[r][2] > kk) kk = s_key[r][2];
            if (s_key[r][3] > kk) kk = s_key[r][3];
            if (kk == 0ull) {
                s_cstar[r] = -1;
            } else {
                s_cstar[r] = 4095 - (int)(kk & 0xFFFull);
                s_nstar[r] = __uint_as_float((uint32_t)(kk >> 12));
            }
        }
    }
    __syncthreads();

    const int   c0 = s_cstar[0], c1 = s_cstar[1];
    const float n0 = s_nstar[0], n1 = s_nstar[1];

    // rank(c*) = count of columns (excluding pos) sorting before c* in stable desc order
    int cnt0 = 0, cnt1 = 0;
    #pragma unroll
    for (int k = 0; k < 16; ++k) {
        const int c = ((tid + ((k >> 2) << 8)) << 2) | (k & 3);
        if (c0 >= 0 && c != pos0 && (nz0[k] > n0 || (nz0[k] == n0 && c < c0))) cnt0++;
        if (c1 >= 0 && c != pos1 && (nz1[k] > n1 || (nz1[k] == n1 && c < c1))) cnt1++;
        if (c == c0) s_sstar[0] = sc0[k];   // owner thread publishes score at c*
        if (c == c1) s_sstar[1] = sc1[k];
    }
    #pragma unroll
    for (int off = 32; off; off >>= 1) {
        cnt0 += __shfl_xor(cnt0, off);
        cnt1 += __shfl_xor(cnt1, off);
    }
    if ((tid & 63) == 0) { s_cnt[0][wv] = cnt0; s_cnt[1][wv] = cnt1; }
    __syncthreads();

    if (tid == 0) {
        float total = 0.0f;
        const int rank0 = s_cnt[0][0] + s_cnt[0][1] + s_cnt[0][2] + s_cnt[0][3];
        const int rank1 = s_cnt[1][0] + s_cnt[1][1] + s_cnt[1][2] + s_cnt[1][3];
        if (c0 >= 0 && rank0 < 64) {
            const float margin = (1.0f - psc0) + s_sstar[0];   // exact JAX loss op order
            total += logf(floorf(4095.0f / (float)(rank0 + 1))) * margin;
        }
        if (c1 >= 0 && rank1 < 64) {
            const float margin = (1.0f - psc1) + s_sstar[1];
            total += logf(floorf(4095.0f / (float)(rank1 + 1))) * margin;
        }
        if (total != 0.0f) atomicAdd(out, total);
    }
}

extern "C" void kernel_launch(void* const* d_in, const int* in_sizes, int n_in,
                              void* d_out, int out_size, void* d_ws, size_t ws_size,
                              hipStream_t stream) {
    const float* inputs  = (const float*)d_in[0];
    const float* targets = (const float*)d_in[1];
    float* out = (float*)d_out;

    // d_out is poisoned before every launch — zero it, then accumulate.
    hipMemsetAsync(out, 0, sizeof(float), stream);
    warp_loss_main<<<dim3(HALF_ROWS), dim3(256), 0, stream>>>(inputs, targets, out);
}

// Round 4
// 529.879 us; speedup vs baseline: 1.0030x; 1.0030x over previous
//
#include <hip/hip_runtime.h>
#include <stdint.h>

#define NLBL      4096
#define HALF_ROWS 8192
#define HALF_CNT  33554432u   // B*NL/2 = 2^25
#define TPB       512

__device__ __forceinline__ uint32_t rotl32(uint32_t x, uint32_t r) {
    return (x << r) | (x >> (32u - r));
}

// JAX threefry2x32 with key (0, 42)  [jax.random.key(42)]
__device__ __forceinline__ void threefry2x32(uint32_t x0, uint32_t x1,
                                             uint32_t& o0, uint32_t& o1) {
    const uint32_t ks0 = 0u;
    const uint32_t ks1 = 42u;
    const uint32_t ks2 = 0x1BD11BDAu ^ ks0 ^ ks1;
    x0 += ks0; x1 += ks1;
#define TF_RND(r) x0 += x1; x1 = rotl32(x1, (r)); x1 ^= x0;
    TF_RND(13u) TF_RND(15u) TF_RND(26u) TF_RND(6u)
    x0 += ks1; x1 += ks2 + 1u;
    TF_RND(17u) TF_RND(29u) TF_RND(16u) TF_RND(24u)
    x0 += ks2; x1 += ks0 + 2u;
    TF_RND(13u) TF_RND(15u) TF_RND(26u) TF_RND(6u)
    x0 += ks0; x1 += ks1 + 3u;
    TF_RND(17u) TF_RND(29u) TF_RND(16u) TF_RND(24u)
    x0 += ks1; x1 += ks2 + 4u;
    TF_RND(13u) TF_RND(15u) TF_RND(26u) TF_RND(6u)
    x0 += ks2; x1 += ks0 + 5u;
#undef TF_RND
    o0 = x0; o1 = x1;
}

// NOTE: JAX uniform = bitcast((bits>>9)|0x3F800000)-1.0, strictly monotone in
// (bits>>9). All the algorithm needs is comparisons, so we keep ub = bits>>9
// as u32 and never convert to float. Equal ub <=> equal uniform (tie case).

__global__ void __launch_bounds__(TPB, 8)
warp_loss_main(const float* __restrict__ inputs,
               const float* __restrict__ targets,
               float* __restrict__ out)
{
    const int b   = blockIdx.x;            // row pair (b, b+8192)
    const int tid = threadIdx.x;
    const size_t r0 = (size_t)b * NLBL;
    const size_t r1 = (size_t)(b + HALF_ROWS) * NLBL;

    const float4* in0 = reinterpret_cast<const float4*>(inputs  + r0);
    const float4* in1 = reinterpret_cast<const float4*>(inputs  + r1);
    const float4* tg0 = reinterpret_cast<const float4*>(targets + r0);
    const float4* tg1 = reinterpret_cast<const float4*>(targets + r1);

    __shared__ int                s_pos[2];
    __shared__ float              s_psc[2];
    __shared__ unsigned long long s_key[2][8];
    __shared__ int                s_cnt[2][8];
    __shared__ int                s_cstar[2];
    __shared__ uint32_t           s_nb[2];
    __shared__ float              s_sstar[2];

    float    sc0[8], sc1[8];
    uint32_t ub0[8], ub1[8];
    const uint32_t cbase0 = (uint32_t)b * NLBL;

    #pragma unroll
    for (int kc = 0; kc < 2; ++kc) {
        const int v4 = tid + (kc << 9);          // float4 index within the row
        const float4 t0 = tg0[v4];
        const float4 t1 = tg1[v4];
        const float4 a0 = in0[v4];
        const float4 a1 = in1[v4];
        const int c = v4 << 2;

        sc0[kc*4+0] = a0.x; sc0[kc*4+1] = a0.y; sc0[kc*4+2] = a0.z; sc0[kc*4+3] = a0.w;
        sc1[kc*4+0] = a1.x; sc1[kc*4+1] = a1.y; sc1[kc*4+2] = a1.z; sc1[kc*4+3] = a1.w;

        if (t0.x > 0.5f) { s_pos[0] = c + 0; s_psc[0] = a0.x; }
        if (t0.y > 0.5f) { s_pos[0] = c + 1; s_psc[0] = a0.y; }
        if (t0.z > 0.5f) { s_pos[0] = c + 2; s_psc[0] = a0.z; }
        if (t0.w > 0.5f) { s_pos[0] = c + 3; s_psc[0] = a0.w; }
        if (t1.x > 0.5f) { s_pos[1] = c + 0; s_psc[1] = a1.x; }
        if (t1.y > 0.5f) { s_pos[1] = c + 1; s_psc[1] = a1.y; }
        if (t1.z > 0.5f) { s_pos[1] = c + 2; s_psc[1] = a1.z; }
        if (t1.w > 0.5f) { s_pos[1] = c + 3; s_psc[1] = a1.w; }

        #pragma unroll
        for (int j = 0; j < 4; ++j) {
            const uint32_t i = cbase0 + (uint32_t)(c + j);
            uint32_t o0, o1;
            threefry2x32(i, i + HALF_CNT, o0, o1);
            ub0[kc*4+j] = o0 >> 9;
            ub1[kc*4+j] = o1 >> 9;
        }
    }
    __syncthreads();

    const int   pos0 = s_pos[0], pos1 = s_pos[1];
    const float psc0 = s_psc[0], psc1 = s_psc[1];

    // Best-noise hit per row: hit = ((1+score)-pos_score) > 0 (exact JAX op
    // order), c != pos.  key = ((ub+1)<<12) | (4095-c): max-key == (max noise,
    // tie min c); key==0 <=> no hit.
    unsigned long long key0 = 0ull, key1 = 0ull;
    #pragma unroll
    for (int k = 0; k < 8; ++k) {
        const int c = (tid << 2) + ((k >> 2) << 11) + (k & 3);
        const float m0 = (1.0f + sc0[k]) - psc0;
        const float m1 = (1.0f + sc1[k]) - psc1;
        if (c != pos0 && m0 > 0.0f) {
            const unsigned long long kk =
                ((unsigned long long)(ub0[k] + 1u) << 12) | (unsigned long long)(4095 - c);
            if (kk > key0) key0 = kk;
        }
        if (c != pos1 && m1 > 0.0f) {
            const unsigned long long kk =
                ((unsigned long long)(ub1[k] + 1u) << 12) | (unsigned long long)(4095 - c);
            if (kk > key1) key1 = kk;
        }
    }
    #pragma unroll
    for (int off = 32; off; off >>= 1) {
        const unsigned long long q0 = __shfl_xor(key0, off);
        const unsigned long long q1 = __shfl_xor(key1, off);
        if (q0 > key0) key0 = q0;
        if (q1 > key1) key1 = q1;
    }
    const int wv = tid >> 6;
    if ((tid & 63) == 0) { s_key[0][wv] = key0; s_key[1][wv] = key1; }
    __syncthreads();
    if (tid == 0) {
        #pragma unroll
        for (int r = 0; r < 2; ++r) {
            unsigned long long kk = s_key[r][0];
            #pragma unroll
            for (int w = 1; w < 8; ++w) if (s_key[r][w] > kk) kk = s_key[r][w];
            if (kk == 0ull) {
                s_cstar[r] = -1;
                s_nb[r]    = 0xFFFFFFFFu;
            } else {
                s_cstar[r] = 4095 - (int)(kk & 0xFFFull);
                s_nb[r]    = (uint32_t)(kk >> 12) - 1u;
            }
        }
    }
    __syncthreads();

    const int      c0  = s_cstar[0], c1  = s_cstar[1];
    const uint32_t nb0 = s_nb[0],    nb1 = s_nb[1];

    // rank(c*) = #{c != pos : ub > ub* or (ub == ub* and c < c*)}
    int cnt0 = 0, cnt1 = 0;
    #pragma unroll
    for (int k = 0; k < 8; ++k) {
        const int c = (tid << 2) + ((k >> 2) << 11) + (k & 3);
        if (c0 >= 0 && c != pos0 && (ub0[k] > nb0 || (ub0[k] == nb0 && c < c0))) cnt0++;
        if (c1 >= 0 && c != pos1 && (ub1[k] > nb1 || (ub1[k] == nb1 && c < c1))) cnt1++;
        if (c == c0) s_sstar[0] = sc0[k];   // owner publishes score at c*
        if (c == c1) s_sstar[1] = sc1[k];
    }
    #pragma unroll
    for (int off = 32; off; off >>= 1) {
        cnt0 += __shfl_xor(cnt0, off);
        cnt1 += __shfl_xor(cnt1, off);
    }
    if ((tid & 63) == 0) { s_cnt[0][wv] = cnt0; s_cnt[1][wv] = cnt1; }
    __syncthreads();

    if (tid == 0) {
        float total = 0.0f;
        int rank0 = 0, rank1 = 0;
        #pragma unroll
        for (int w = 0; w < 8; ++w) { rank0 += s_cnt[0][w]; rank1 += s_cnt[1][w]; }
        if (c0 >= 0 && rank0 < 64) {
            const float margin = (1.0f - psc0) + s_sstar[0];   // exact JAX loss op order
            total += logf(floorf(4095.0f / (float)(rank0 + 1))) * margin;
        }
        if (c1 >= 0 && rank1 < 64) {
            const float margin = (1.0f - psc1) + s_sstar[1];
            total += logf(floorf(4095.0f / (float)(rank1 + 1))) * margin;
        }
        if (total != 0.0f) atomicAdd(out, total);
    }
}

extern "C" void kernel_launch(void* const* d_in, const int* in_sizes, int n_in,
                              void* d_out, int out_size, void* d_ws, size_t ws_size,
                              hipStream_t stream) {
    const float* inputs  = (const float*)d_in[0];
    const float* targets = (const float*)d_in[1];
    float* out = (float*)d_out;

    // d_out is poisoned before every launch — zero it, then accumulate.
    hipMemsetAsync(out, 0, sizeof(float), stream);
    warp_loss_main<<<dim3(HALF_ROWS), dim3(TPB), 0, stream>>>(inputs, targets, out);
}

// Round 5
// 526.102 us; speedup vs baseline: 1.0102x; 1.0072x over previous
//
#include <hip/hip_runtime.h>
#include <stdint.h>

#define NLBL      4096
#define HALF_ROWS 8192
#define HALF_CNT  33554432u   // B*NL/2 = 2^25
#define TPB       512

__device__ __forceinline__ uint32_t rotl32(uint32_t x, uint32_t r) {
    return (x << r) | (x >> (32u - r));
}

// JAX threefry2x32 with key (0, 42)  [jax.random.key(42)]
__device__ __forceinline__ void threefry2x32(uint32_t x0, uint32_t x1,
                                             uint32_t& o0, uint32_t& o1) {
    const uint32_t ks0 = 0u;
    const uint32_t ks1 = 42u;
    const uint32_t ks2 = 0x1BD11BDAu ^ ks0 ^ ks1;
    x0 += ks0; x1 += ks1;
#define TF_RND(r) x0 += x1; x1 = rotl32(x1, (r)); x1 ^= x0;
    TF_RND(13u) TF_RND(15u) TF_RND(26u) TF_RND(6u)
    x0 += ks1; x1 += ks2 + 1u;
    TF_RND(17u) TF_RND(29u) TF_RND(16u) TF_RND(24u)
    x0 += ks2; x1 += ks0 + 2u;
    TF_RND(13u) TF_RND(15u) TF_RND(26u) TF_RND(6u)
    x0 += ks0; x1 += ks1 + 3u;
    TF_RND(17u) TF_RND(29u) TF_RND(16u) TF_RND(24u)
    x0 += ks1; x1 += ks2 + 4u;
    TF_RND(13u) TF_RND(15u) TF_RND(26u) TF_RND(6u)
    x0 += ks2; x1 += ks0 + 5u;
#undef TF_RND
    o0 = x0; o1 = x1;
}

// JAX uniform = bitcast((bits>>9)|0x3F800000)-1.0 — strictly monotone in
// (bits>>9); we only ever COMPARE noise, so keep ub = bits>>9 as u32.

__global__ void __launch_bounds__(TPB)
warp_loss_main(const float* __restrict__ inputs,
               const float* __restrict__ targets,
               float* __restrict__ out)
{
    const int b   = blockIdx.x;            // row pair (b, b+8192)
    const int tid = threadIdx.x;
    const size_t r0 = (size_t)b * NLBL;
    const size_t r1 = (size_t)(b + HALF_ROWS) * NLBL;

    const float4* in0 = reinterpret_cast<const float4*>(inputs  + r0);
    const float4* in1 = reinterpret_cast<const float4*>(inputs  + r1);
    const float4* tg0 = reinterpret_cast<const float4*>(targets + r0);
    const float4* tg1 = reinterpret_cast<const float4*>(targets + r1);

    // Scores round-trip through LDS so only ub[16] stays live across barriers.
    __shared__ float              s_sc[2][NLBL];        // 32 KB
    __shared__ int                s_pos[2];
    __shared__ float              s_psc[2];
    __shared__ unsigned long long s_key[2][8];
    __shared__ unsigned int       s_cnt[8];
    __shared__ int                s_cstar[2];
    __shared__ uint32_t           s_nb[2];

    uint32_t ub0[8], ub1[8];
    const uint32_t cbase0 = (uint32_t)b * NLBL;

    #pragma unroll
    for (int kc = 0; kc < 2; ++kc) {
        const int v4 = tid + (kc << 9);          // float4 index within the row
        const int c  = v4 << 2;

        // Issue all 4 global loads first; threefry below is independent of
        // them, so ~300 cy of PRNG VALU hides the HBM latency.
        const float4 a0 = in0[v4];
        const float4 a1 = in1[v4];
        const float4 t0 = tg0[v4];
        const float4 t1 = tg1[v4];

        #pragma unroll
        for (int j = 0; j < 4; ++j) {
            const uint32_t i = cbase0 + (uint32_t)(c + j);
            uint32_t o0, o1;
            threefry2x32(i, i + HALF_CNT, o0, o1);
            ub0[kc*4+j] = o0 >> 9;
            ub1[kc*4+j] = o1 >> 9;
        }

        // Consume loads: stage scores to LDS, detect the positive.
        reinterpret_cast<float4*>(s_sc[0])[v4] = a0;
        reinterpret_cast<float4*>(s_sc[1])[v4] = a1;

        if (t0.x > 0.5f) { s_pos[0] = c + 0; s_psc[0] = a0.x; }
        if (t0.y > 0.5f) { s_pos[0] = c + 1; s_psc[0] = a0.y; }
        if (t0.z > 0.5f) { s_pos[0] = c + 2; s_psc[0] = a0.z; }
        if (t0.w > 0.5f) { s_pos[0] = c + 3; s_psc[0] = a0.w; }
        if (t1.x > 0.5f) { s_pos[1] = c + 0; s_psc[1] = a1.x; }
        if (t1.y > 0.5f) { s_pos[1] = c + 1; s_psc[1] = a1.y; }
        if (t1.z > 0.5f) { s_pos[1] = c + 2; s_psc[1] = a1.z; }
        if (t1.w > 0.5f) { s_pos[1] = c + 3; s_psc[1] = a1.w; }
    }
    __syncthreads();

    const int   pos0 = s_pos[0], pos1 = s_pos[1];
    const float psc0 = s_psc[0], psc1 = s_psc[1];

    // Phase 2 — best-noise hit per row: hit = ((1+score)-pos_score) > 0
    // (exact JAX op order), c != pos.  key = ((ub+1)<<12)|(4095-c):
    // max-key == (max noise, tie min c); key==0 <=> no hit.
    unsigned long long key0 = 0ull, key1 = 0ull;
    #pragma unroll
    for (int kc = 0; kc < 2; ++kc) {
        const int v4 = tid + (kc << 9);
        const float4 x0 = reinterpret_cast<const float4*>(s_sc[0])[v4];
        const float4 x1 = reinterpret_cast<const float4*>(s_sc[1])[v4];
        const float q0[4] = { x0.x, x0.y, x0.z, x0.w };
        const float q1[4] = { x1.x, x1.y, x1.z, x1.w };
        #pragma unroll
        for (int j = 0; j < 4; ++j) {
            const int c = (v4 << 2) + j;
            const int k = kc*4 + j;
            const float m0 = (1.0f + q0[j]) - psc0;
            const float m1 = (1.0f + q1[j]) - psc1;
            if (c != pos0 && m0 > 0.0f) {
                const unsigned long long kk =
                    ((unsigned long long)(ub0[k] + 1u) << 12) | (unsigned long long)(4095 - c);
                if (kk > key0) key0 = kk;
            }
            if (c != pos1 && m1 > 0.0f) {
                const unsigned long long kk =
                    ((unsigned long long)(ub1[k] + 1u) << 12) | (unsigned long long)(4095 - c);
                if (kk > key1) key1 = kk;
            }
        }
    }
    #pragma unroll
    for (int off = 32; off; off >>= 1) {
        const unsigned long long q0 = __shfl_xor(key0, off);
        const unsigned long long q1 = __shfl_xor(key1, off);
        if (q0 > key0) key0 = q0;
        if (q1 > key1) key1 = q1;
    }
    const int wv = tid >> 6;
    if ((tid & 63) == 0) { s_key[0][wv] = key0; s_key[1][wv] = key1; }
    __syncthreads();
    if (tid == 0) {
        #pragma unroll
        for (int r = 0; r < 2; ++r) {
            unsigned long long kk = s_key[r][0];
            #pragma unroll
            for (int w = 1; w < 8; ++w) if (s_key[r][w] > kk) kk = s_key[r][w];
            if (kk == 0ull) {
                s_cstar[r] = -1;
                s_nb[r]    = 0xFFFFFFFFu;
            } else {
                s_cstar[r] = 4095 - (int)(kk & 0xFFFull);
                s_nb[r]    = (uint32_t)(kk >> 12) - 1u;
            }
        }
    }
    __syncthreads();

    const int      c0  = s_cstar[0], c1  = s_cstar[1];
    const uint32_t nb0 = s_nb[0],    nb1 = s_nb[1];

    // Phase 3 — rank(c*) = #{c != pos : ub > ub* or (ub == ub* and c < c*)}.
    // Both rows' counts packed into one u32 (<= 4096 each, 16-bit fields).
    uint32_t cnt = 0;
    #pragma unroll
    for (int k = 0; k < 8; ++k) {
        const int c = (tid << 2) + ((k >> 2) << 11) + (k & 3);
        if (c0 >= 0 && c != pos0 && (ub0[k] > nb0 || (ub0[k] == nb0 && c < c0))) cnt += 1u;
        if (c1 >= 0 && c != pos1 && (ub1[k] > nb1 || (ub1[k] == nb1 && c < c1))) cnt += 1u << 16;
    }
    #pragma unroll
    for (int off = 32; off; off >>= 1) cnt += __shfl_xor(cnt, off);
    if ((tid & 63) == 0) s_cnt[wv] = cnt;
    __syncthreads();

    if (tid == 0) {
        uint32_t tot = 0;
        #pragma unroll
        for (int w = 0; w < 8; ++w) tot += s_cnt[w];
        const int rank0 = (int)(tot & 0xFFFFu);
        const int rank1 = (int)(tot >> 16);
        float total = 0.0f;
        if (c0 >= 0 && rank0 < 64) {
            const float margin = (1.0f - psc0) + s_sc[0][c0];   // exact JAX loss op order
            total += logf(floorf(4095.0f / (float)(rank0 + 1))) * margin;
        }
        if (c1 >= 0 && rank1 < 64) {
            const float margin = (1.0f - psc1) + s_sc[1][c1];
            total += logf(floorf(4095.0f / (float)(rank1 + 1))) * margin;
        }
        if (total != 0.0f) atomicAdd(out, total);
    }
}

extern "C" void kernel_launch(void* const* d_in, const int* in_sizes, int n_in,
                              void* d_out, int out_size, void* d_ws, size_t ws_size,
                              hipStream_t stream) {
    const float* inputs  = (const float*)d_in[0];
    const float* targets = (const float*)d_in[1];
    float* out = (float*)d_out;

    // d_out is poisoned before every launch — zero it, then accumulate.
    hipMemsetAsync(out, 0, sizeof(float), stream);
    warp_loss_main<<<dim3(HALF_ROWS), dim3(TPB), 0, stream>>>(inputs, targets, out);
}

// Round 8
// 520.202 us; speedup vs baseline: 1.0216x; 1.0113x over previous
//
#include <hip/hip_runtime.h>
#include <stdint.h>

#define NLBL      4096
#define HALF_ROWS 8192
#define HALF_CNT  33554432u   // B*NL/2 = 2^25
#define TPB       512

// Force v_alignbit_b32: rotl(x,r) == funnel-shift-right by (32-r) of x:x.
__device__ __forceinline__ uint32_t rotl32(uint32_t x, uint32_t r) {
    return __builtin_amdgcn_alignbit(x, x, 32u - r);
}

// JAX threefry2x32 with key (0, 42)  [jax.random.key(42)]
__device__ __forceinline__ void threefry2x32(uint32_t x0, uint32_t x1,
                                             uint32_t& o0, uint32_t& o1) {
    const uint32_t ks0 = 0u;
    const uint32_t ks1 = 42u;
    const uint32_t ks2 = 0x1BD11BDAu ^ ks0 ^ ks1;
    x0 += ks0; x1 += ks1;
#define TF_RND(r) x0 += x1; x1 = rotl32(x1, (r)); x1 ^= x0;
    TF_RND(13u) TF_RND(15u) TF_RND(26u) TF_RND(6u)
    x0 += ks1; x1 += ks2 + 1u;
    TF_RND(17u) TF_RND(29u) TF_RND(16u) TF_RND(24u)
    x0 += ks2; x1 += ks0 + 2u;
    TF_RND(13u) TF_RND(15u) TF_RND(26u) TF_RND(6u)
    x0 += ks0; x1 += ks1 + 3u;
    TF_RND(17u) TF_RND(29u) TF_RND(16u) TF_RND(24u)
    x0 += ks1; x1 += ks2 + 4u;
    TF_RND(13u) TF_RND(15u) TF_RND(26u) TF_RND(6u)
    x0 += ks2; x1 += ks0 + 5u;
#undef TF_RND
    o0 = x0; o1 = x1;
}

// JAX uniform = bitcast((bits>>9)|0x3F800000)-1.0 — strictly monotone in
// (bits>>9); we only ever COMPARE noise, so keep ub = bits>>9 as u32.

__global__ void __launch_bounds__(TPB)
warp_loss_main(const float* __restrict__ inputs,
               const float* __restrict__ targets,
               float* __restrict__ part)
{
    const int b   = blockIdx.x;            // row pair (b, b+8192)
    const int tid = threadIdx.x;
    const size_t r0 = (size_t)b * NLBL;
    const size_t r1 = (size_t)(b + HALF_ROWS) * NLBL;

    const float4* in0 = reinterpret_cast<const float4*>(inputs  + r0);
    const float4* in1 = reinterpret_cast<const float4*>(inputs  + r1);
    const float4* tg0 = reinterpret_cast<const float4*>(targets + r0);
    const float4* tg1 = reinterpret_cast<const float4*>(targets + r1);

    __shared__ float              s_sc[2][NLBL];        // 32 KB score stage
    __shared__ int                s_pos[2];
    __shared__ unsigned long long s_key[2][8];
    __shared__ unsigned int       s_cnt[8];

    uint32_t ub0[8], ub1[8];
    const uint32_t cbase0 = (uint32_t)b * NLBL;

    // ---- Phase 1: issue ALL global loads, then threefry x8 hides latency ----
    const int v4a = tid;              // float4 idx, first half of row
    const int v4b = tid + 512;        // second half
    const float4 a0A = in0[v4a];
    const float4 a0B = in0[v4b];
    const float4 a1A = in1[v4a];
    const float4 a1B = in1[v4b];
    const float4 t0A = tg0[v4a];
    const float4 t0B = tg0[v4b];
    const float4 t1A = tg1[v4a];
    const float4 t1B = tg1[v4b];

    #pragma unroll
    for (int kc = 0; kc < 2; ++kc) {
        const int c = (tid + (kc << 9)) << 2;
        #pragma unroll
        for (int j = 0; j < 4; ++j) {
            const uint32_t i = cbase0 + (uint32_t)(c + j);
            uint32_t o0, o1;
            threefry2x32(i, i + HALF_CNT, o0, o1);
            ub0[kc*4+j] = o0 >> 9;
            ub1[kc*4+j] = o1 >> 9;
        }
    }

    // Consume loads: stage scores, detect the positive (1 branch per row/half).
    reinterpret_cast<float4*>(s_sc[0])[v4a] = a0A;
    reinterpret_cast<float4*>(s_sc[0])[v4b] = a0B;
    reinterpret_cast<float4*>(s_sc[1])[v4a] = a1A;
    reinterpret_cast<float4*>(s_sc[1])[v4b] = a1B;

    {
        const int cA = v4a << 2, cB = v4b << 2;
        if (t0A.x > 0.5f || t0A.y > 0.5f || t0A.z > 0.5f || t0A.w > 0.5f)
            s_pos[0] = cA + (t0A.x > 0.5f ? 0 : (t0A.y > 0.5f ? 1 : (t0A.z > 0.5f ? 2 : 3)));
        if (t0B.x > 0.5f || t0B.y > 0.5f || t0B.z > 0.5f || t0B.w > 0.5f)
            s_pos[0] = cB + (t0B.x > 0.5f ? 0 : (t0B.y > 0.5f ? 1 : (t0B.z > 0.5f ? 2 : 3)));
        if (t1A.x > 0.5f || t1A.y > 0.5f || t1A.z > 0.5f || t1A.w > 0.5f)
            s_pos[1] = cA + (t1A.x > 0.5f ? 0 : (t1A.y > 0.5f ? 1 : (t1A.z > 0.5f ? 2 : 3)));
        if (t1B.x > 0.5f || t1B.y > 0.5f || t1B.z > 0.5f || t1B.w > 0.5f)
            s_pos[1] = cB + (t1B.x > 0.5f ? 0 : (t1B.y > 0.5f ? 1 : (t1B.z > 0.5f ? 2 : 3)));
    }
    __syncthreads();

    const int   pos0 = s_pos[0],       pos1 = s_pos[1];
    const float psc0 = s_sc[0][pos0];  // broadcast LDS reads
    const float psc1 = s_sc[1][pos1];

    // ---- Phase 2: best-noise hit per row.  hit = ((1+score)-pos_score) > 0
    // (exact JAX op order), c != pos.  key = ((ub+1)<<12)|(4095-c):
    // max-key == (max noise, tie min c); key==0 <=> no hit. ----
    unsigned long long key0 = 0ull, key1 = 0ull;
    #pragma unroll
    for (int kc = 0; kc < 2; ++kc) {
        const int v4 = tid + (kc << 9);
        const float4 x0 = reinterpret_cast<const float4*>(s_sc[0])[v4];
        const float4 x1 = reinterpret_cast<const float4*>(s_sc[1])[v4];
        const float q0[4] = { x0.x, x0.y, x0.z, x0.w };
        const float q1[4] = { x1.x, x1.y, x1.z, x1.w };
        #pragma unroll
        for (int j = 0; j < 4; ++j) {
            const int c = (v4 << 2) + j;
            const int k = kc*4 + j;
            const float m0 = (1.0f + q0[j]) - psc0;
            const float m1 = (1.0f + q1[j]) - psc1;
            if (c != pos0 && m0 > 0.0f) {
                const unsigned long long kk =
                    ((unsigned long long)(ub0[k] + 1u) << 12) | (unsigned long long)(4095 - c);
                if (kk > key0) key0 = kk;
            }
            if (c != pos1 && m1 > 0.0f) {
                const unsigned long long kk =
                    ((unsigned long long)(ub1[k] + 1u) << 12) | (unsigned long long)(4095 - c);
                if (kk > key1) key1 = kk;
            }
        }
    }
    #pragma unroll
    for (int off = 32; off; off >>= 1) {
        const unsigned long long q0 = __shfl_xor(key0, off);
        const unsigned long long q1 = __shfl_xor(key1, off);
        if (q0 > key0) key0 = q0;
        if (q1 > key1) key1 = q1;
    }
    const int wv = tid >> 6;
    if ((tid & 63) == 0) { s_key[0][wv] = key0; s_key[1][wv] = key1; }
    __syncthreads();

    // All threads merge the 8 per-wave keys redundantly (broadcast reads) —
    // removes the serialized tid0 section + one barrier.
    unsigned long long kk0 = s_key[0][0], kk1 = s_key[1][0];
    #pragma unroll
    for (int w = 1; w < 8; ++w) {
        if (s_key[0][w] > kk0) kk0 = s_key[0][w];
        if (s_key[1][w] > kk1) kk1 = s_key[1][w];
    }
    const int      c0  = (kk0 == 0ull) ? -1 : 4095 - (int)(kk0 & 0xFFFull);
    const int      c1  = (kk1 == 0ull) ? -1 : 4095 - (int)(kk1 & 0xFFFull);
    const uint32_t nb0 = (kk0 == 0ull) ? 0xFFFFFFFFu : (uint32_t)(kk0 >> 12) - 1u;
    const uint32_t nb1 = (kk1 == 0ull) ? 0xFFFFFFFFu : (uint32_t)(kk1 >> 12) - 1u;

    // ---- Phase 3: rank(c*) = #{c != pos : ub > ub* or (ub == ub* and c < c*)}
    // Both rows packed into one u32 (16-bit fields). ----
    uint32_t cnt = 0;
    #pragma unroll
    for (int k = 0; k < 8; ++k) {
        const int c = (tid << 2) + ((k >> 2) << 11) + (k & 3);
        if (c0 >= 0 && c != pos0 && (ub0[k] > nb0 || (ub0[k] == nb0 && c < c0))) cnt += 1u;
        if (c1 >= 0 && c != pos1 && (ub1[k] > nb1 || (ub1[k] == nb1 && c < c1))) cnt += 1u << 16;
    }
    #pragma unroll
    for (int off = 32; off; off >>= 1) cnt += __shfl_xor(cnt, off);
    if ((tid & 63) == 0) s_cnt[wv] = cnt;
    __syncthreads();

    if (tid == 0) {
        uint32_t tot = 0;
        #pragma unroll
        for (int w = 0; w < 8; ++w) tot += s_cnt[w];
        const int rank0 = (int)(tot & 0xFFFFu);
        const int rank1 = (int)(tot >> 16);
        float total = 0.0f;
        if (c0 >= 0 && rank0 < 64) {
            const float margin = (1.0f - psc0) + s_sc[0][c0];   // exact JAX loss op order
            total += logf(floorf(4095.0f / (float)(rank0 + 1))) * margin;
        }
        if (c1 >= 0 && rank1 < 64) {
            const float margin = (1.0f - psc1) + s_sc[1][c1];
            total += logf(floorf(4095.0f / (float)(rank1 + 1))) * margin;
        }
        part[b] = total;     // per-block partial — no same-address atomic
    }
}

// 8192 partials -> single float.  One block, 1024 threads, 8 floats each.
__global__ void __launch_bounds__(1024)
warp_loss_reduce(const float* __restrict__ part, float* __restrict__ out)
{
    const int tid = threadIdx.x;
    const float4 a = reinterpret_cast<const float4*>(part)[tid];
    const float4 b = reinterpret_cast<const float4*>(part)[tid + 1024];
    float s = ((a.x + a.y) + (a.z + a.w)) + ((b.x + b.y) + (b.z + b.w));
    #pragma unroll
    for (int off = 32; off; off >>= 1) s += __shfl_xor(s, off);
    __shared__ float sm[16];
    if ((tid & 63) == 0) sm[tid >> 6] = s;
    __syncthreads();
    if (tid == 0) {
        float t = 0.0f;
        #pragma unroll
        for (int w = 0; w < 16; ++w) t += sm[w];
        out[0] = t;
    }
}

extern "C" void kernel_launch(void* const* d_in, const int* in_sizes, int n_in,
                              void* d_out, int out_size, void* d_ws, size_t ws_size,
                              hipStream_t stream) {
    const float* inputs  = (const float*)d_in[0];
    const float* targets = (const float*)d_in[1];
    float* out  = (float*)d_out;
    float* part = (float*)d_ws;          // 8192 floats = 32 KB scratch

    warp_loss_main  <<<dim3(HALF_ROWS), dim3(TPB),  0, stream>>>(inputs, targets, part);
    warp_loss_reduce<<<dim3(1),         dim3(1024), 0, stream>>>(part, out);
}